// Round 8
// baseline (150.439 us; speedup 1.0000x reference)
//
#include <hip/hip_runtime.h>
#include <hip/hip_bf16.h>

#define B_ 2
#define N_ 8192
#define NC_ 512
#define D_ 512
#define H_ 16
#define HD_ 32
#define SCALE_ 0.17677669529663687f
#define LOG2E_ 1.4426950408889634f
#define EPS_ 1e-6f
#define NCHUNK 32
#define CHUNK (N_ / NCHUNK)   // 256 keys per chunk

typedef __attribute__((ext_vector_type(8))) short bf16x8_t;
typedef __attribute__((ext_vector_type(4))) short bf16x4_t;
typedef __attribute__((ext_vector_type(4))) float f32x4_t;

static __device__ __forceinline__ short f2bf(float f) {
    unsigned u = __float_as_uint(f);
    unsigned r = (u + 0x7FFFu + ((u >> 16) & 1u)) >> 16;
    return (short)r;
}

// native v_exp_f32 (D = 2^S0)
static __device__ __forceinline__ float fast_exp2(float x) {
#if __has_builtin(__builtin_amdgcn_exp2f)
    return __builtin_amdgcn_exp2f(x);
#else
    float r; asm("v_exp_f32 %0, %1" : "=v"(r) : "v"(x)); return r;
#endif
}

static __device__ __forceinline__ void gload_lds16(const short* g, void* l) {
    __builtin_amdgcn_global_load_lds(
        (const __attribute__((address_space(1))) void*)g,
        (__attribute__((address_space(3))) void*)l, 16, 0, 0);
}

// ---------------------------------------------------------------------------
// Transpose + convert weights: W[512][ncols] fp32 -> WT[ncols][512] bf16.
// ---------------------------------------------------------------------------
__global__ __launch_bounds__(256) void transpose_cvt_kernel(
    const float* __restrict__ Wq, const float* __restrict__ Wkv,
    const float* __restrict__ Wout,
    short* __restrict__ WqT, short* __restrict__ WkvT, short* __restrict__ WoutT)
{
    const float* src; short* dst; int ncols;
    if (blockIdx.z == 0)      { src = Wq;   dst = WqT;   ncols = 512; }
    else if (blockIdx.z == 1) { src = Wkv;  dst = WkvT;  ncols = 1024; }
    else                      { src = Wout; dst = WoutT; ncols = 512; }
    if ((int)blockIdx.x * 32 >= ncols) return;

    __shared__ short t[32][34];
    const int c0 = blockIdx.x * 32, r0 = blockIdx.y * 32;
    const int tc = threadIdx.x & 31, tr = threadIdx.x >> 5;
#pragma unroll
    for (int i = 0; i < 4; i++) {
        int r = tr + i * 8;
        t[tc][r] = f2bf(src[(size_t)(r0 + r) * ncols + c0 + tc]);
    }
    __syncthreads();
#pragma unroll
    for (int i = 0; i < 4; i++) {
        int outr = tr + i * 8;
        dst[(size_t)(c0 + outr) * 512 + r0 + tc] = t[outr][tc];
    }
}

// ---------------------------------------------------------------------------
// bf16 GEMM (B-transposed): C[M][N] = A[M][K] @ BT[N][K]^T, epilogue scale.
// m97 structure: 128x128 tile, BK=32, linear LDS. B staged via
// global_load_lds(16B). A either bf16 (global_load_lds) or fp32 (reg-staged
// with fused fp32->bf16 conversion -- saves the separate cvt pass).
// ---------------------------------------------------------------------------
template <bool OUT_BF16, bool A_FP32>
__global__ __launch_bounds__(256) void gemm_bt_kernel(
    const void* __restrict__ Av, const short* __restrict__ BT,
    void* __restrict__ C, int M, int N, int K, float oscale)
{
    __shared__ short As[128 * 32];
    __shared__ short Bs[128 * 32];

    const int tid = threadIdx.x;
    const int wid = tid >> 6, lane = tid & 63;
    const int l16 = lane & 15, lg = lane >> 4;
    const int wr = (wid >> 1) * 64, wc = (wid & 1) * 64;

    const int nwg = gridDim.x * gridDim.y;
    const int flat = blockIdx.y * gridDim.x + blockIdx.x;
    const int swz = (flat & 7) * (nwg >> 3) + (flat >> 3);   // nwg % 8 == 0
    const int bx = swz % gridDim.x, by = swz / gridDim.x;

    const f32x4_t zero4 = {0.f, 0.f, 0.f, 0.f};
    f32x4_t acc[4][4];
#pragma unroll
    for (int i = 0; i < 4; i++)
#pragma unroll
        for (int j = 0; j < 4; j++) acc[i][j] = zero4;

    // A staging pointers
    const short* aptr = nullptr;        // bf16 path
    const float* aptr_f = nullptr;      // fp32 path
    const int arow = tid >> 1, ak = (tid & 1) * 16;
    if (A_FP32)
        aptr_f = (const float*)Av + (size_t)(by * 128 + arow) * K + ak;
    else
        aptr = (const short*)Av + (size_t)(by * 128 + wid * 16 + (lane >> 2)) * K + (lane & 3) * 8;

    const short* bptr = BT + (size_t)(bx * 128 + wid * 16 + (lane >> 2)) * K + (lane & 3) * 8;
    char* al = (char*)As + wid * 1024;
    char* bl = (char*)Bs + wid * 1024;
    const size_t rstep = (size_t)64 * K;

    for (int kt = 0; kt < K; kt += 32) {
        if (A_FP32) {
            const float* ap = aptr_f + kt;
            float4 f0 = *(const float4*)(ap);
            float4 f1 = *(const float4*)(ap + 4);
            float4 f2 = *(const float4*)(ap + 8);
            float4 f3 = *(const float4*)(ap + 12);
            bf16x8_t h0 = {f2bf(f0.x), f2bf(f0.y), f2bf(f0.z), f2bf(f0.w),
                           f2bf(f1.x), f2bf(f1.y), f2bf(f1.z), f2bf(f1.w)};
            bf16x8_t h1 = {f2bf(f2.x), f2bf(f2.y), f2bf(f2.z), f2bf(f2.w),
                           f2bf(f3.x), f2bf(f3.y), f2bf(f3.z), f2bf(f3.w)};
            *(bf16x8_t*)&As[arow * 32 + ak]     = h0;
            *(bf16x8_t*)&As[arow * 32 + ak + 8] = h1;
        } else {
            gload_lds16(aptr + kt, al);
            gload_lds16(aptr + rstep + kt, al + 4096);
        }
        gload_lds16(bptr + kt, bl);
        gload_lds16(bptr + rstep + kt, bl + 4096);
        __syncthreads();

        bf16x8_t bfr[4];
#pragma unroll
        for (int nf = 0; nf < 4; nf++)
            bfr[nf] = *(const bf16x8_t*)&Bs[(wc + nf * 16 + l16) * 32 + lg * 8];
#pragma unroll
        for (int mf = 0; mf < 4; mf++) {
            bf16x8_t afr = *(const bf16x8_t*)&As[(wr + mf * 16 + l16) * 32 + lg * 8];
#pragma unroll
            for (int nf = 0; nf < 4; nf++)
                acc[mf][nf] = __builtin_amdgcn_mfma_f32_16x16x32_bf16(
                    afr, bfr[nf], acc[mf][nf], 0, 0, 0);
        }
        __syncthreads();
    }

#pragma unroll
    for (int mf = 0; mf < 4; mf++) {
#pragma unroll
        for (int nf = 0; nf < 4; nf++) {
            int row0 = by * 128 + wr + mf * 16 + lg * 4;
            int col  = bx * 128 + wc + nf * 16 + l16;
#pragma unroll
            for (int r = 0; r < 4; r++) {
                float v = acc[mf][nf][r] * oscale;
                if (OUT_BF16)
                    ((short*)C)[(size_t)(row0 + r) * N + col] = f2bf(v);
                else
                    ((float*)C)[(size_t)(row0 + r) * N + col] = v;
            }
        }
    }
}

// ---------------------------------------------------------------------------
// Attention (round-6 structure, measured 58.4 us): block = (chunk, h, b);
// 4 waves x 128 cluster rows; 32-key tiles; sequential halves (one s[8]
// live -> VGPR<=128, 4 waves/SIMD); native v_exp_f32 (q pre-scaled by
// SCALE*log2e); K/V prefetch at tile top; double-buffered v_t/reds ->
// 2 barriers/tile; swizzled 32KB P LDS.
// ---------------------------------------------------------------------------
__global__ __launch_bounds__(256) void attn_kernel(
    const short* __restrict__ qb,    // [B*NC][D] bf16 (pre-scaled)
    const short* __restrict__ kvb,   // [B*N][2D] bf16
    short* __restrict__ out_part,    // [NCHUNK][B][H][NC][HD] bf16
    float* __restrict__ ts_part)     // [NCHUNK][B][H][NC]
{
    const int chunk = blockIdx.x, h = blockIdx.y, b = blockIdx.z;
    const int tid = threadIdx.x, wid = tid >> 6, lane = tid & 63;
    const int l16 = lane & 15, lg = lane >> 4;

    __shared__ short P_lds[512 * 32];     // swizzled, 32 KB (same-wave use only)
    __shared__ short v_t[2][32][40];      // [buf][d][key], double-buffered
    __shared__ float reds[2][2][4][16];   // [buf][half][wave][col]

    bf16x8_t qf[8];
#pragma unroll
    for (int mf = 0; mf < 8; mf++) {
        int row = wid * 128 + mf * 16 + l16;
        qf[mf] = *(const bf16x8_t*)&qb[(size_t)(b * NC_ + row) * D_ + h * HD_ + lg * 8];
    }

    const f32x4_t zero4 = {0.f, 0.f, 0.f, 0.f};
    f32x4_t oacc[8][2], tsacc[8];
#pragma unroll
    for (int mf = 0; mf < 8; mf++) {
        oacc[mf][0] = zero4; oacc[mf][1] = zero4; tsacc[mf] = zero4;
    }
    bf16x8_t onesf;
#pragma unroll
    for (int j = 0; j < 8; j++) onesf[j] = (short)0x3F80;   // bf16 1.0

    const short* kptr = kvb + (size_t)(b * N_ + chunk * CHUNK + l16) * (2 * D_) + h * HD_ + lg * 8;
    const int skey = tid >> 3, sd0 = (tid & 7) * 4;
    const short* vptr = kvb + (size_t)(b * N_ + chunk * CHUNK + skey) * (2 * D_) + D_ + h * HD_ + sd0;
    char* Pb = (char*)P_lds;

    for (int kt = 0; kt < CHUNK / 32; kt++) {
        const int cur = kt & 1;
        const size_t koff = (size_t)kt * 32 * (2 * D_);

        // issue all global loads for this tile up front (latency overlap)
        bf16x8_t kf0 = *(const bf16x8_t*)(kptr + koff);
        bf16x8_t kf1 = *(const bf16x8_t*)(kptr + koff + 16 * (2 * D_));
        bf16x4_t vv  = *(const bf16x4_t*)(vptr + koff);
        v_t[cur][sd0 + 0][skey] = vv[0];
        v_t[cur][sd0 + 1][skey] = vv[1];
        v_t[cur][sd0 + 2][skey] = vv[2];
        v_t[cur][sd0 + 3][skey] = vv[3];

#pragma unroll
        for (int half = 0; half < 2; half++) {
            f32x4_t s[8];
            bf16x8_t kf = half ? kf1 : kf0;
#pragma unroll
            for (int mf = 0; mf < 8; mf++)
                s[mf] = __builtin_amdgcn_mfma_f32_16x16x32_bf16(qf[mf], kf, zero4, 0, 0, 0);

            float sl = 0.f;
#pragma unroll
            for (int mf = 0; mf < 8; mf++)
#pragma unroll
                for (int r = 0; r < 4; r++) {
                    float e = fast_exp2(s[mf][r]);
                    s[mf][r] = e; sl += e;
                }
            sl += __shfl_xor(sl, 16, 64);
            sl += __shfl_xor(sl, 32, 64);
            if (lane < 16) reds[cur][half][wid][lane] = sl;
            __syncthreads();
            float inv = __fdividef(1.f, reds[cur][half][0][l16] + reds[cur][half][1][l16] +
                                        reds[cur][half][2][l16] + reds[cur][half][3][l16]);

            // write P (truncating f32->bf16), swizzled 16B-unit layout
            const int kbyte = (l16 & 7) * 2;
            const int ku = (l16 >> 3) + half * 2;
#pragma unroll
            for (int mf = 0; mf < 8; mf++) {
#pragma unroll
                for (int r = 0; r < 4; r++) {
                    int row = wid * 128 + mf * 16 + lg * 4 + r;
                    int x = (row >> 1) & 3;
                    int by0 = row * 64 + kbyte + (((ku ^ x) & 3) << 4);
                    *(short*)(Pb + by0) = (short)(__float_as_uint(s[mf][r] * inv) >> 16);
                }
            }
        }

        // PV + ts (reads own wave's P rows; same-wave DS ordering)
        bf16x8_t v0 = *(const bf16x8_t*)&v_t[cur][l16][lg * 8];
        bf16x8_t v1 = *(const bf16x8_t*)&v_t[cur][16 + l16][lg * 8];
#pragma unroll
        for (int mf = 0; mf < 8; mf++) {
            int row = wid * 128 + mf * 16 + l16;
            bf16x8_t pa = *(const bf16x8_t*)(Pb + row * 64 +
                              (((lg ^ ((row >> 1) & 3)) & 3) << 4));
            oacc[mf][0] = __builtin_amdgcn_mfma_f32_16x16x32_bf16(pa, v0, oacc[mf][0], 0, 0, 0);
            oacc[mf][1] = __builtin_amdgcn_mfma_f32_16x16x32_bf16(pa, v1, oacc[mf][1], 0, 0, 0);
            tsacc[mf]   = __builtin_amdgcn_mfma_f32_16x16x32_bf16(pa, onesf, tsacc[mf], 0, 0, 0);
        }
    }

    const size_t base = ((size_t)(chunk * B_ + b) * H_ + h);
#pragma unroll
    for (int mf = 0; mf < 8; mf++) {
        int row0 = wid * 128 + mf * 16 + lg * 4;
#pragma unroll
        for (int nf = 0; nf < 2; nf++) {
            int col = nf * 16 + l16;
#pragma unroll
            for (int r = 0; r < 4; r++)
                out_part[(base * NC_ + row0 + r) * HD_ + col] = f2bf(oacc[mf][nf][r]);
        }
        if (l16 == 0) {
#pragma unroll
            for (int r = 0; r < 4; r++)
                ts_part[base * NC_ + row0 + r] = tsacc[mf][r];
        }
    }
}

// ---------------------------------------------------------------------------
// Reduce chunk partials (bf16), apply /(ts+eps), emit token_sizes + out_mid.
// ---------------------------------------------------------------------------
__global__ __launch_bounds__(256) void reduce_kernel(
    const short* __restrict__ out_part, const float* __restrict__ ts_part,
    short* __restrict__ out_mid, float* __restrict__ tok_out)
{
    const int bnc = blockIdx.x;
    const int b = bnc >> 9, nc = bnc & 511;
    const int t = threadIdx.x;
    __shared__ float tsh[16];
    if (t < 16) {
        float s = 0.f;
#pragma unroll
        for (int ch = 0; ch < NCHUNK; ch++)
            s += ts_part[((size_t)(ch * B_ + b) * H_ + t) * NC_ + nc];
        tsh[t] = s;
    }
    __syncthreads();
    if (t == 0) {
        float s = 0.f;
#pragma unroll
        for (int i = 0; i < 16; i++) s += tsh[i];
        tok_out[b * NC_ + nc] = s * (1.f / 16.f);
    }
    for (int c = t; c < D_; c += 256) {
        int hh = c >> 5, d = c & 31;
        float s = 0.f;
#pragma unroll
        for (int ch = 0; ch < NCHUNK; ch++) {
            unsigned short u = (unsigned short)
                out_part[(((size_t)(ch * B_ + b) * H_ + hh) * NC_ + nc) * HD_ + d];
            s += __uint_as_float((unsigned)u << 16);
        }
        out_mid[(size_t)(b * NC_ + nc) * D_ + c] = f2bf(s / (tsh[hh] + EPS_));
    }
}

// ---------------------------------------------------------------------------
extern "C" void kernel_launch(void* const* d_in, const int* in_sizes, int n_in,
                              void* d_out, int out_size, void* d_ws, size_t ws_size,
                              hipStream_t stream)
{
    (void)in_sizes; (void)n_in; (void)out_size; (void)ws_size;
    const float* x        = (const float*)d_in[0];
    const float* clusters = (const float*)d_in[1];
    const float* Wq       = (const float*)d_in[2];
    const float* Wkv      = (const float*)d_in[3];
    const float* Wout     = (const float*)d_in[4];

    char* ws = (char*)d_ws;
    // early phase (dead before attn):
    short* WkvT     = (short*)(ws);                 //  1,048,576 [dead after kv gemm]
    short* WqT      = (short*)(ws + 1048576);       //    524,288 [dead after q gemm]
    // attn phase onward:
    short* out_part = (short*)(ws);                 // 33,554,432 bf16 [over dead WkvT/WqT]
    float* ts_part  = (float*)(ws + 33554432);      //  2,097,152
    short* kvb      = (short*)(ws + 35651584);      // 33,554,432 [dead after attn]
    short* out_mid  = (short*)(ws + 35651584);      //  1,048,576 [reduce, over kvb]
    short* qb       = (short*)(ws + 69206016);      //  1,048,576
    short* WoutT    = (short*)(ws + 70254592);      //    524,288
    // total 70,778,880 bytes (same footprint as rounds 2-7)

    float* out = (float*)d_out;
    float* tok = out + (size_t)B_ * NC_ * D_;

    // 1. transpose+convert weights
    transpose_cvt_kernel<<<dim3(32, 16, 3), dim3(256), 0, stream>>>(
        Wq, Wkv, Wout, WqT, WkvT, WoutT);
    // 2. kv = x @ Wkv (fp32 A fused-converted, bf16 out)
    gemm_bt_kernel<true, true><<<dim3((2 * D_) / 128, (B_ * N_) / 128), dim3(256), 0, stream>>>(
        x, WkvT, kvb, B_ * N_, 2 * D_, D_, 1.0f);
    // 3. q = clusters @ Wq (fp32 A fused-converted, bf16 out, pre-scaled)
    gemm_bt_kernel<true, true><<<dim3(D_ / 128, (B_ * NC_) / 128), dim3(256), 0, stream>>>(
        clusters, WqT, qb, B_ * NC_, D_, D_, SCALE_ * LOG2E_);
    // 4. attention partials
    attn_kernel<<<dim3(NCHUNK, H_, B_), dim3(256), 0, stream>>>(
        qb, kvb, out_part, ts_part);
    // 5. reduce + normalize + token_sizes
    reduce_kernel<<<dim3(B_ * NC_), dim3(256), 0, stream>>>(
        out_part, ts_part, out_mid, tok);
    // 6. out = out_mid @ Wout (bf16 A via global_load_lds, fp32 out)
    gemm_bt_kernel<false, false><<<dim3(D_ / 128, (B_ * NC_) / 128), dim3(256), 0, stream>>>(
        out_mid, WoutT, d_out, B_ * NC_, D_, D_, 1.0f);
}

// Round 9
// 133.609 us; speedup vs baseline: 1.1260x; 1.1260x over previous
//
#include <hip/hip_runtime.h>
#include <hip/hip_bf16.h>

#define B_ 2
#define N_ 8192
#define NC_ 512
#define D_ 512
#define H_ 16
#define HD_ 32
#define SCALE_ 0.17677669529663687f
#define LOG2E_ 1.4426950408889634f
#define EPS_ 1e-6f
#define NCHUNK 32
#define CHUNK (N_ / NCHUNK)   // 256 keys per chunk

typedef __attribute__((ext_vector_type(8))) short bf16x8_t;
typedef __attribute__((ext_vector_type(4))) short bf16x4_t;
typedef __attribute__((ext_vector_type(4))) float f32x4_t;

static __device__ __forceinline__ short f2bf(float f) {
    unsigned u = __float_as_uint(f);
    unsigned r = (u + 0x7FFFu + ((u >> 16) & 1u)) >> 16;
    return (short)r;
}

// native v_exp_f32 (D = 2^S0)
static __device__ __forceinline__ float fast_exp2(float x) {
#if __has_builtin(__builtin_amdgcn_exp2f)
    return __builtin_amdgcn_exp2f(x);
#else
    float r; asm("v_exp_f32 %0, %1" : "=v"(r) : "v"(x)); return r;
#endif
}

// one u32 holding two truncated bf16: low half = trunc(lo), high = trunc(hi)
static __device__ __forceinline__ unsigned pack_trunc(float lo, float hi) {
    return __builtin_amdgcn_perm(__float_as_uint(hi), __float_as_uint(lo), 0x07060302u);
}

static __device__ __forceinline__ float bf2f(short s) {
    return __uint_as_float((unsigned)(unsigned short)s << 16);
}

static __device__ __forceinline__ void gload_lds16(const short* g, void* l) {
    __builtin_amdgcn_global_load_lds(
        (const __attribute__((address_space(1))) void*)g,
        (__attribute__((address_space(3))) void*)l, 16, 0, 0);
}

// ---------------------------------------------------------------------------
// Convert fp32 -> bf16, two source/dest pairs, 8 elems/thread, no tail.
// ---------------------------------------------------------------------------
__global__ __launch_bounds__(256) void cvt_bf16_kernel(
    const float* __restrict__ a, short* __restrict__ ao, int na8,
    const float* __restrict__ b, short* __restrict__ bo)
{
    int i8 = blockIdx.x * 256 + threadIdx.x;
    const float* src; short* dst;
    if (i8 < na8) { src = a + (size_t)i8 * 8; dst = ao + (size_t)i8 * 8; }
    else { size_t o = (size_t)(i8 - na8) * 8; src = b + o; dst = bo + o; }
    float4 v0 = *(const float4*)src;
    float4 v1 = *(const float4*)(src + 4);
    bf16x8_t p = {f2bf(v0.x), f2bf(v0.y), f2bf(v0.z), f2bf(v0.w),
                  f2bf(v1.x), f2bf(v1.y), f2bf(v1.z), f2bf(v1.w)};
    *(bf16x8_t*)dst = p;
}

// ---------------------------------------------------------------------------
// Transpose + convert weights: W[512][ncols] fp32 -> WT[ncols][512] bf16.
// ---------------------------------------------------------------------------
__global__ __launch_bounds__(256) void transpose_cvt_kernel(
    const float* __restrict__ Wq, const float* __restrict__ Wkv,
    const float* __restrict__ Wout,
    short* __restrict__ WqT, short* __restrict__ WkvT, short* __restrict__ WoutT)
{
    const float* src; short* dst; int ncols;
    if (blockIdx.z == 0)      { src = Wq;   dst = WqT;   ncols = 512; }
    else if (blockIdx.z == 1) { src = Wkv;  dst = WkvT;  ncols = 1024; }
    else                      { src = Wout; dst = WoutT; ncols = 512; }
    if ((int)blockIdx.x * 32 >= ncols) return;

    __shared__ short t[32][34];
    const int c0 = blockIdx.x * 32, r0 = blockIdx.y * 32;
    const int tc = threadIdx.x & 31, tr = threadIdx.x >> 5;
#pragma unroll
    for (int i = 0; i < 4; i++) {
        int r = tr + i * 8;
        t[tc][r] = f2bf(src[(size_t)(r0 + r) * ncols + c0 + tc]);
    }
    __syncthreads();
#pragma unroll
    for (int i = 0; i < 4; i++) {
        int outr = tr + i * 8;
        dst[(size_t)(c0 + outr) * 512 + r0 + tc] = t[outr][tc];
    }
}

// ---------------------------------------------------------------------------
// bf16 GEMM (B-transposed): C[M][N] = A[M][K] @ BT[N][K]^T, epilogue scale.
// m97 structure: 128x128 tile, BK=32, linear LDS + global_load_lds(16B).
// ---------------------------------------------------------------------------
template <bool OUT_BF16>
__global__ __launch_bounds__(256) void gemm_bt_kernel(
    const short* __restrict__ A, const short* __restrict__ BT,
    void* __restrict__ C, int M, int N, int K, float oscale)
{
    __shared__ short As[128 * 32];
    __shared__ short Bs[128 * 32];

    const int tid = threadIdx.x;
    const int wid = tid >> 6, lane = tid & 63;
    const int l16 = lane & 15, lg = lane >> 4;
    const int wr = (wid >> 1) * 64, wc = (wid & 1) * 64;

    const int nwg = gridDim.x * gridDim.y;
    const int flat = blockIdx.y * gridDim.x + blockIdx.x;
    const int swz = (flat & 7) * (nwg >> 3) + (flat >> 3);   // nwg % 8 == 0
    const int bx = swz % gridDim.x, by = swz / gridDim.x;

    const f32x4_t zero4 = {0.f, 0.f, 0.f, 0.f};
    f32x4_t acc[4][4];
#pragma unroll
    for (int i = 0; i < 4; i++)
#pragma unroll
        for (int j = 0; j < 4; j++) acc[i][j] = zero4;

    const short* aptr = A + (size_t)(by * 128 + wid * 16 + (lane >> 2)) * K + (lane & 3) * 8;
    const short* bptr = BT + (size_t)(bx * 128 + wid * 16 + (lane >> 2)) * K + (lane & 3) * 8;
    char* al = (char*)As + wid * 1024;
    char* bl = (char*)Bs + wid * 1024;
    const size_t rstep = (size_t)64 * K;

    for (int kt = 0; kt < K; kt += 32) {
        gload_lds16(aptr + kt, al);
        gload_lds16(aptr + rstep + kt, al + 4096);
        gload_lds16(bptr + kt, bl);
        gload_lds16(bptr + rstep + kt, bl + 4096);
        __syncthreads();

        bf16x8_t bfr[4];
#pragma unroll
        for (int nf = 0; nf < 4; nf++)
            bfr[nf] = *(const bf16x8_t*)&Bs[(wc + nf * 16 + l16) * 32 + lg * 8];
#pragma unroll
        for (int mf = 0; mf < 4; mf++) {
            bf16x8_t afr = *(const bf16x8_t*)&As[(wr + mf * 16 + l16) * 32 + lg * 8];
#pragma unroll
            for (int nf = 0; nf < 4; nf++)
                acc[mf][nf] = __builtin_amdgcn_mfma_f32_16x16x32_bf16(
                    afr, bfr[nf], acc[mf][nf], 0, 0, 0);
        }
        __syncthreads();
    }

#pragma unroll
    for (int mf = 0; mf < 4; mf++) {
#pragma unroll
        for (int nf = 0; nf < 4; nf++) {
            int row0 = by * 128 + wr + mf * 16 + lg * 4;
            int col  = bx * 128 + wc + nf * 16 + l16;
#pragma unroll
            for (int r = 0; r < 4; r++) {
                float v = acc[mf][nf][r] * oscale;
                if (OUT_BF16)
                    ((short*)C)[(size_t)(row0 + r) * N + col] = f2bf(v);
                else
                    ((float*)C)[(size_t)(row0 + r) * N + col] = v;
            }
        }
    }
}

// ---------------------------------------------------------------------------
// Attention, per-key-normalization folded into V: block = (chunk, h, b);
// 4 waves x 128 cluster rows; 32-key tiles. P_lds holds UNNORMALIZED e
// (written right after exp, same-wave use only). Column sums exchanged via
// reds; ONE barrier per tile; after it each lane builds inv[k] for its 8
// keys and scales its V fragments (V' = inv*V) and the ts B-frag (= inv).
// K/V prefetched one tile ahead. Swizzled 32KB P LDS; native v_exp_f32.
// ---------------------------------------------------------------------------
__global__ __launch_bounds__(256) void attn_kernel(
    const short* __restrict__ qb,    // [B*NC][D] bf16 (pre-scaled)
    const short* __restrict__ kvb,   // [B*N][2D] bf16
    short* __restrict__ out_part,    // [NCHUNK][B][H][NC][HD] bf16
    float* __restrict__ ts_part)     // [NCHUNK][B][H][NC]
{
    const int chunk = blockIdx.x, h = blockIdx.y, b = blockIdx.z;
    const int tid = threadIdx.x, wid = tid >> 6, lane = tid & 63;
    const int l16 = lane & 15, lg = lane >> 4;

    __shared__ short P_lds[512 * 32];     // swizzled, 32 KB (same-wave use only)
    __shared__ short v_t[2][32][40];      // [buf][d][key], double-buffered
    __shared__ float reds[2][4][32];      // [buf][wave][key] column-sum partials

    bf16x8_t qf[8];
#pragma unroll
    for (int mf = 0; mf < 8; mf++) {
        int row = wid * 128 + mf * 16 + l16;
        qf[mf] = *(const bf16x8_t*)&qb[(size_t)(b * NC_ + row) * D_ + h * HD_ + lg * 8];
    }

    const f32x4_t zero4 = {0.f, 0.f, 0.f, 0.f};
    f32x4_t oacc[8][2], tsacc[8];
#pragma unroll
    for (int mf = 0; mf < 8; mf++) {
        oacc[mf][0] = zero4; oacc[mf][1] = zero4; tsacc[mf] = zero4;
    }

    const short* kptr = kvb + (size_t)(b * N_ + chunk * CHUNK + l16) * (2 * D_) + h * HD_ + lg * 8;
    const int skey = tid >> 3, sd0 = (tid & 7) * 4;
    const short* vptr = kvb + (size_t)(b * N_ + chunk * CHUNK + skey) * (2 * D_) + D_ + h * HD_ + sd0;
    char* Pb = (char*)P_lds;

    // prologue: prefetch tile 0's K halves and V
    bf16x8_t kf0 = *(const bf16x8_t*)(kptr);
    bf16x8_t kf1 = *(const bf16x8_t*)(kptr + 16 * (2 * D_));
    bf16x4_t vv  = *(const bf16x4_t*)(vptr);

    for (int kt = 0; kt < CHUNK / 32; kt++) {
        const int cur = kt & 1;

        // stage this tile's V (prefetched last iteration)
        v_t[cur][sd0 + 0][skey] = vv[0];
        v_t[cur][sd0 + 1][skey] = vv[1];
        v_t[cur][sd0 + 2][skey] = vv[2];
        v_t[cur][sd0 + 3][skey] = vv[3];

#pragma unroll
        for (int half = 0; half < 2; half++) {
            f32x4_t s[8];
            bf16x8_t kf = half ? kf1 : kf0;
#pragma unroll
            for (int mf = 0; mf < 8; mf++)
                s[mf] = __builtin_amdgcn_mfma_f32_16x16x32_bf16(qf[mf], kf, zero4, 0, 0, 0);

            // exp, write UNNORMALIZED e to P_lds, accumulate column sum
            const int kbyte = (l16 & 7) * 2;
            const int ku = (l16 >> 3) + half * 2;
            float sl = 0.f;
#pragma unroll
            for (int mf = 0; mf < 8; mf++) {
#pragma unroll
                for (int r = 0; r < 4; r++) {
                    float e = fast_exp2(s[mf][r]);
                    sl += e;
                    int row = wid * 128 + mf * 16 + lg * 4 + r;
                    int x = (row >> 1) & 3;
                    *(short*)(Pb + row * 64 + kbyte + (((ku ^ x) & 3) << 4)) =
                        (short)(__float_as_uint(e) >> 16);
                }
            }
            sl += __shfl_xor(sl, 16, 64);
            sl += __shfl_xor(sl, 32, 64);
            if (lane < 16) reds[cur][wid][half * 16 + lane] = sl;
        }

        // prefetch next tile's K/V (wraps harmlessly on last tile)
        {
            const size_t koffn = (size_t)((kt + 1) & (CHUNK / 32 - 1)) * 32 * (2 * D_);
            kf0 = *(const bf16x8_t*)(kptr + koffn);
            kf1 = *(const bf16x8_t*)(kptr + koffn + 16 * (2 * D_));
            vv  = *(const bf16x4_t*)(vptr + koffn);
        }

        __syncthreads();   // reds + v_t ready; P_lds is same-wave only

        // per-lane totals for keys lg*8..lg*8+7
        f32x4_t ta = *(const f32x4_t*)&reds[cur][0][lg * 8];
        f32x4_t tb = *(const f32x4_t*)&reds[cur][0][lg * 8 + 4];
#pragma unroll
        for (int w = 1; w < 4; w++) {
            ta += *(const f32x4_t*)&reds[cur][w][lg * 8];
            tb += *(const f32x4_t*)&reds[cur][w][lg * 8 + 4];
        }
        float iv[8];
#pragma unroll
        for (int r = 0; r < 4; r++) {
            iv[r]     = __fdividef(1.f, ta[r]);
            iv[4 + r] = __fdividef(1.f, tb[r]);
        }

        // scale V fragments by inv[key] and build ts B-frag (= inv)
        bf16x8_t v0r = *(const bf16x8_t*)&v_t[cur][l16][lg * 8];
        bf16x8_t v1r = *(const bf16x8_t*)&v_t[cur][16 + l16][lg * 8];
        bf16x8_t v0, v1, invf;
        {
            unsigned* p0 = (unsigned*)&v0;
            unsigned* p1 = (unsigned*)&v1;
            unsigned* pi = (unsigned*)&invf;
#pragma unroll
            for (int j = 0; j < 4; j++) {
                float a0 = bf2f(v0r[2 * j])     * iv[2 * j];
                float a1 = bf2f(v0r[2 * j + 1]) * iv[2 * j + 1];
                float b0 = bf2f(v1r[2 * j])     * iv[2 * j];
                float b1 = bf2f(v1r[2 * j + 1]) * iv[2 * j + 1];
                p0[j] = pack_trunc(a0, a1);
                p1[j] = pack_trunc(b0, b1);
                pi[j] = pack_trunc(iv[2 * j], iv[2 * j + 1]);
            }
        }

        // PV + ts (reads own wave's P rows; same-wave DS ordering)
#pragma unroll
        for (int mf = 0; mf < 8; mf++) {
            int row = wid * 128 + mf * 16 + l16;
            bf16x8_t pa = *(const bf16x8_t*)(Pb + row * 64 +
                              (((lg ^ ((row >> 1) & 3)) & 3) << 4));
            oacc[mf][0] = __builtin_amdgcn_mfma_f32_16x16x32_bf16(pa, v0, oacc[mf][0], 0, 0, 0);
            oacc[mf][1] = __builtin_amdgcn_mfma_f32_16x16x32_bf16(pa, v1, oacc[mf][1], 0, 0, 0);
            tsacc[mf]   = __builtin_amdgcn_mfma_f32_16x16x32_bf16(pa, invf, tsacc[mf], 0, 0, 0);
        }
    }

    const size_t base = ((size_t)(chunk * B_ + b) * H_ + h);
#pragma unroll
    for (int mf = 0; mf < 8; mf++) {
        int row0 = wid * 128 + mf * 16 + lg * 4;
#pragma unroll
        for (int nf = 0; nf < 2; nf++) {
            int col = nf * 16 + l16;
#pragma unroll
            for (int r = 0; r < 4; r++)
                out_part[(base * NC_ + row0 + r) * HD_ + col] = f2bf(oacc[mf][nf][r]);
        }
        if (l16 == 0) {
#pragma unroll
            for (int r = 0; r < 4; r++)
                ts_part[base * NC_ + row0 + r] = tsacc[mf][r];
        }
    }
}

// ---------------------------------------------------------------------------
// Reduce chunk partials (bf16), apply /(ts+eps), emit token_sizes + out_mid.
// ---------------------------------------------------------------------------
__global__ __launch_bounds__(256) void reduce_kernel(
    const short* __restrict__ out_part, const float* __restrict__ ts_part,
    short* __restrict__ out_mid, float* __restrict__ tok_out)
{
    const int bnc = blockIdx.x;
    const int b = bnc >> 9, nc = bnc & 511;
    const int t = threadIdx.x;
    __shared__ float tsh[16];
    if (t < 16) {
        float s = 0.f;
#pragma unroll
        for (int ch = 0; ch < NCHUNK; ch++)
            s += ts_part[((size_t)(ch * B_ + b) * H_ + t) * NC_ + nc];
        tsh[t] = s;
    }
    __syncthreads();
    if (t == 0) {
        float s = 0.f;
#pragma unroll
        for (int i = 0; i < 16; i++) s += tsh[i];
        tok_out[b * NC_ + nc] = s * (1.f / 16.f);
    }
    for (int c = t; c < D_; c += 256) {
        int hh = c >> 5, d = c & 31;
        float s = 0.f;
#pragma unroll
        for (int ch = 0; ch < NCHUNK; ch++) {
            unsigned short u = (unsigned short)
                out_part[(((size_t)(ch * B_ + b) * H_ + hh) * NC_ + nc) * HD_ + d];
            s += __uint_as_float((unsigned)u << 16);
        }
        out_mid[(size_t)(b * NC_ + nc) * D_ + c] = f2bf(s / (tsh[hh] + EPS_));
    }
}

// ---------------------------------------------------------------------------
extern "C" void kernel_launch(void* const* d_in, const int* in_sizes, int n_in,
                              void* d_out, int out_size, void* d_ws, size_t ws_size,
                              hipStream_t stream)
{
    (void)in_sizes; (void)n_in; (void)out_size; (void)ws_size;
    const float* x        = (const float*)d_in[0];
    const float* clusters = (const float*)d_in[1];
    const float* Wq       = (const float*)d_in[2];
    const float* Wkv      = (const float*)d_in[3];
    const float* Wout     = (const float*)d_in[4];

    char* ws = (char*)d_ws;
    short* x_bf     = (short*)(ws);                 // 16,777,216 [dead after kv gemm]
    short* WkvT     = (short*)(ws + 16777216);      //  1,048,576 [dead after kv gemm]
    short* cl_bf    = (short*)(ws + 17825792);      //  1,048,576 [dead after q gemm]
    short* WqT      = (short*)(ws + 18874368);      //    524,288 [dead after q gemm]
    short* out_part = (short*)(ws);                 // 33,554,432 bf16 [attn, over dead]
    float* ts_part  = (float*)(ws + 33554432);      //  2,097,152
    short* kvb      = (short*)(ws + 35651584);      // 33,554,432 [dead after attn]
    short* out_mid  = (short*)(ws + 35651584);      //  1,048,576 [reduce, over kvb]
    short* qb       = (short*)(ws + 69206016);      //  1,048,576
    short* WoutT    = (short*)(ws + 70254592);      //    524,288
    // total 70,778,880 bytes

    float* out = (float*)d_out;
    float* tok = out + (size_t)B_ * NC_ * D_;

    // 1. convert x + clusters to bf16
    cvt_bf16_kernel<<<dim3(4352), dim3(256), 0, stream>>>(
        x, x_bf, (B_ * N_ * D_) / 8, clusters, cl_bf);
    // 2. transpose+convert weights
    transpose_cvt_kernel<<<dim3(32, 16, 3), dim3(256), 0, stream>>>(
        Wq, Wkv, Wout, WqT, WkvT, WoutT);
    // 3. kv = x @ Wkv (bf16)
    gemm_bt_kernel<true><<<dim3((2 * D_) / 128, (B_ * N_) / 128), dim3(256), 0, stream>>>(
        x_bf, WkvT, kvb, B_ * N_, 2 * D_, D_, 1.0f);
    // 4. q = clusters @ Wq (bf16, pre-scaled by SCALE*log2e for exp2 softmax)
    gemm_bt_kernel<true><<<dim3(D_ / 128, (B_ * NC_) / 128), dim3(256), 0, stream>>>(
        cl_bf, WqT, qb, B_ * NC_, D_, D_, SCALE_ * LOG2E_);
    // 5. attention partials
    attn_kernel<<<dim3(NCHUNK, H_, B_), dim3(256), 0, stream>>>(
        qb, kvb, out_part, ts_part);
    // 6. reduce + normalize + token_sizes
    reduce_kernel<<<dim3(B_ * NC_), dim3(256), 0, stream>>>(
        out_part, ts_part, out_mid, tok);
    // 7. out = out_mid @ Wout (fp32)
    gemm_bt_kernel<false><<<dim3(D_ / 128, (B_ * NC_) / 128), dim3(256), 0, stream>>>(
        out_mid, WoutT, d_out, B_ * NC_, D_, D_, 1.0f);
}